// Round 3
// baseline (40449.716 us; speedup 1.0000x reference)
//
#include <hip/hip_runtime.h>
#include <stdint.h>

#define B_ 16
#define S_ 2048
#define H_ 512
#define M_ (B_ * S_)  // 32768 rows in all big GEMMs

// ---------------------------------------------------------------------------
// GEMM: Y[M,N] = X[M,K] @ W[N,K]^T + b1[N] (+ b2[N]), optional tanh epilogue.
// 128x128 tile, BK=16, 256 threads, 8x8 micro-tile per thread. fp32 VALU.
// (unchanged)
// ---------------------------------------------------------------------------
template <int ACT>
__global__ __launch_bounds__(256) void gemm_xwt(
    const float* __restrict__ X, const float* __restrict__ W,
    const float* __restrict__ b1, const float* __restrict__ b2,
    float* __restrict__ Y, int K, int ldy)
{
  __shared__ float As[16][132];
  __shared__ float Bs[16][132];
  const int tid = threadIdx.x;
  const int bm = blockIdx.x, bn = blockIdx.y;
  const int ty = tid >> 4, tx = tid & 15;      // 16x16 thread grid
  const int lr = tid >> 2, lk = (tid & 3) << 2; // staging: 64 rows x 4 k-quads
  const float* Xb = X + (size_t)(bm * 128) * K;
  const float* Wb = W + (size_t)(bn * 128) * K;

  float acc[8][8] = {};

  for (int k0 = 0; k0 < K; k0 += 16) {
    float4 xa0 = *(const float4*)(Xb + (size_t)lr * K + k0 + lk);
    float4 xa1 = *(const float4*)(Xb + (size_t)(lr + 64) * K + k0 + lk);
    float4 wa0 = *(const float4*)(Wb + (size_t)lr * K + k0 + lk);
    float4 wa1 = *(const float4*)(Wb + (size_t)(lr + 64) * K + k0 + lk);
    __syncthreads();
    As[lk + 0][lr] = xa0.x; As[lk + 1][lr] = xa0.y; As[lk + 2][lr] = xa0.z; As[lk + 3][lr] = xa0.w;
    As[lk + 0][lr + 64] = xa1.x; As[lk + 1][lr + 64] = xa1.y; As[lk + 2][lr + 64] = xa1.z; As[lk + 3][lr + 64] = xa1.w;
    Bs[lk + 0][lr] = wa0.x; Bs[lk + 1][lr] = wa0.y; Bs[lk + 2][lr] = wa0.z; Bs[lk + 3][lr] = wa0.w;
    Bs[lk + 0][lr + 64] = wa1.x; Bs[lk + 1][lr + 64] = wa1.y; Bs[lk + 2][lr + 64] = wa1.z; Bs[lk + 3][lr + 64] = wa1.w;
    __syncthreads();
#pragma unroll
    for (int kk = 0; kk < 16; ++kk) {
      float4 a0 = *(const float4*)&As[kk][ty * 8];
      float4 a1 = *(const float4*)&As[kk][ty * 8 + 4];
      float4 b0 = *(const float4*)&Bs[kk][tx * 8];
      float4 b1v = *(const float4*)&Bs[kk][tx * 8 + 4];
      float av[8] = {a0.x, a0.y, a0.z, a0.w, a1.x, a1.y, a1.z, a1.w};
      float bv[8] = {b0.x, b0.y, b0.z, b0.w, b1v.x, b1v.y, b1v.z, b1v.w};
#pragma unroll
      for (int i = 0; i < 8; ++i)
#pragma unroll
        for (int j = 0; j < 8; ++j) acc[i][j] += av[i] * bv[j];
    }
  }

  const int ncol0 = bn * 128 + tx * 8;
  float bias[8];
#pragma unroll
  for (int j = 0; j < 8; ++j) {
    float bb = b1[ncol0 + j];
    if (b2) bb += b2[ncol0 + j];
    bias[j] = bb;
  }
#pragma unroll
  for (int i = 0; i < 8; ++i) {
    size_t row = (size_t)bm * 128 + ty * 8 + i;
    float* yp = Y + row * (size_t)ldy + ncol0;
    float out[8];
#pragma unroll
    for (int j = 0; j < 8; ++j) {
      float v = acc[i][j] + bias[j];
      if (ACT) v = tanhf(v);
      out[j] = v;
    }
    *(float4*)(yp)     = make_float4(out[0], out[1], out[2], out[3]);
    *(float4*)(yp + 4) = make_float4(out[4], out[5], out[6], out[7]);
  }
}

// ---------------------------------------------------------------------------
// Attention fusion (unchanged).
// ---------------------------------------------------------------------------
__global__ __launch_bounds__(256) void fusion_kernel(
    const float* __restrict__ F,    // [M, 1536] = a|v|l
    const float* __restrict__ CTX,  // [M, 512]
    float* __restrict__ FU)         // [M, 512]
{
  const int row = blockIdx.x * 4 + (threadIdx.x >> 6);
  const int lane = threadIdx.x & 63;
  const float* a = F + (size_t)row * 1536;
  const float* v = a + 512;
  const float* l = a + 1024;
  const float* c = CTX + (size_t)row * 512;
  float sa = 0.f, sv = 0.f, sl = 0.f;
  for (int k = lane; k < 512; k += 64) {
    float cv = c[k];
    sa += a[k] * cv; sv += v[k] * cv; sl += l[k] * cv;
  }
#pragma unroll
  for (int off = 1; off < 64; off <<= 1) {
    sa += __shfl_xor(sa, off);
    sv += __shfl_xor(sv, off);
    sl += __shfl_xor(sl, off);
  }
  float m = fmaxf(sa, fmaxf(sv, sl));
  float ea = expf(sa - m), ev = expf(sv - m), el = expf(sl - m);
  float inv = 1.0f / (ea + ev + el);
  float wa = ea * inv, wv = ev * inv, wl = el * inv;
  float* fu = FU + (size_t)row * 512;
  for (int k = lane; k < 512; k += 64)
    fu[k] = wa * a[k] + wv * v[k] + wl * l[k];
}

// ---------------------------------------------------------------------------
// Persistent LSTM v4: v3 dataflow, sync moved into the XCD-local L2.
//
// Post-mortem v3: sentinel spin barely helped -> the cost is raw RT latency
// of agent-scope atomics (serviced at IF$, ~1200cy), 3-4 RTs/step. v4:
//   - DUAL PUBLISH: every tagged word stored twice: WORKGROUP scope
//     (plain store -> local XCD L2: ringL2/sentL2) + AGENT scope
//     (IF$ authoritative copy: ringIF/sentIF). Separate arrays so L2
//     writebacks never race the IF$ copy.
//   - FAST DETECT: consumer polls sentL2 via atomic_fetch_add(+0) at
//     WORKGROUP scope — global atomic RMWs execute AT the L2 (no L1
//     staleness, no fences), ~300cy RT when producer shares the XCD
//     (the %8 round-robin heuristic groups a batch's 16 WGs on one XCD).
//     Every 4th iteration falls back to an AGENT load of sentIF ->
//     guaranteed forward progress even if the XCD mapping changes
//     (perf degrades toward v1; never hangs, never wrong).
//   - FAST PAYLOAD: __threadfence() (invalidates vector L1) then plain
//     WORKGROUP loads of ringL2, tag-verified; retries re-fence, every
//     4th retry reads the AGENT copy. Any tag-matched word is correct
//     regardless of which path supplied it (tag-in-word).
// Math (dot/tail/G-prefetch) bitwise identical to v3. Ring depth 4; tags
// unique per step; 0xAA poison never matches a tag.
// ---------------------------------------------------------------------------
__device__ __forceinline__ float sigf(float x) { return 1.f / (1.f + expf(-x)); }
__device__ __forceinline__ float lo32f(unsigned long long w) {
  return __builtin_bit_cast(float, (unsigned int)w);
}

__global__ __launch_bounds__(256, 1) void lstm_kernel(
    const float* __restrict__ G,    // [B*S, 2048] precomputed x@Wih.T + biases
    const float* __restrict__ Whh,  // [2048, 512]
    const float* __restrict__ h0,   // [B, 512]
    const float* __restrict__ c0,   // [B, 512]
    unsigned long long* __restrict__ ringL2,  // [4][B][512] tagged h (L2 path)
    unsigned long long* __restrict__ ringIF,  // [4][B][512] tagged h (IF$ path)
    unsigned long long* __restrict__ sentL2,  // [4][B][16] sentinels (L2 path)
    unsigned long long* __restrict__ sentIF,  // [4][B][16] sentinels (IF$ path)
    float* __restrict__ r_out,      // [B, S, 512]
    float* __restrict__ hT,         // [B, 512]
    float* __restrict__ cT)         // [B, 512]
{
  const int bi = blockIdx.x;
  const int b  = ((bi & 7) << 1) | ((bi >> 3) & 1);  // 16 WGs/batch -> 1 XCD
  const int wg = bi >> 4;
  const int k0h = wg << 5;  // hidden-slice base (32 units)
  const int tid = threadIdx.x;

  __shared__ float h_lds[2][512];   // double-buffered h
  __shared__ float gates_lds[128];
  __shared__ float c_lds[32];

  // dot-phase mapping (identical to v1/v3)
  const int col = tid >> 1;       // 0..127 local gate row
  const int khalf = tid & 1;      // k-half of the 512-dot
  const int kbase = khalf << 8;   // 0 or 256
  const int g = col >> 5, ul = col & 31;
  const int gcol = g * 512 + k0h + ul;  // row in Whh == column in G

  // Whh slice into registers (AGPR-backed), one-time
  float4 warr[64];
  const float* wsrc = Whh + (size_t)gcol * 512 + kbase;
#pragma unroll
  for (int j = 0; j < 64; ++j) warr[j] = *(const float4*)(wsrc + j * 4);

  const float* gbase = G + (size_t)b * S_ * 2048;

  if (tid < 32) c_lds[tid] = c0[b * H_ + k0h + tid];
  h_lds[0][tid]       = h0[b * H_ + tid];
  h_lds[0][tid + 256] = h0[b * H_ + tid + 256];
  float gval = (khalf == 0) ? gbase[gcol] : 0.f;   // G(0), prefetched
  __syncthreads();

  int buf = 0;
  for (int t = 0; t < S_; ++t) {
    // ---- dot over h(t-1) (bitwise-identical to v1/v3) ----
    const float* hb = &h_lds[buf][kbase];
    float4 s4 = make_float4(0.f, 0.f, 0.f, 0.f);
#pragma unroll
    for (int j = 0; j < 64; ++j) {
      float4 hv = *(const float4*)(hb + (j << 2));
      s4.x += warr[j].x * hv.x;
      s4.y += warr[j].y * hv.y;
      s4.z += warr[j].z * hv.z;
      s4.w += warr[j].w * hv.w;
    }
    float sum = (s4.x + s4.y) + (s4.z + s4.w);
    sum += __shfl_xor(sum, 1);
    if (khalf == 0) gates_lds[col] = sum + gval;
    __syncthreads();   // A: gates ready

    const size_t roff = ((size_t)(t & 3) * B_ + b) * H_;
    unsigned long long* slotL2 = ringL2 + roff;
    unsigned long long* slotIF = ringIF + roff;

    // ---- producer tail: 32 lanes, nonlinearity + dual tagged publish ----
    if (tid < 32) {
      const int u = tid;
      float ip = gates_lds[u], fp = gates_lds[32 + u];
      float gp = gates_lds[64 + u], op = gates_lds[96 + u];
      float ig = sigf(ip), fg = sigf(fp);
      float gg = tanhf(gp), og = sigf(op);
      float cn = fg * c_lds[u] + ig * gg;
      c_lds[u] = cn;
      float hn = og * tanhf(cn);
      unsigned long long pk =
          ((unsigned long long)(unsigned int)t << 32) |
          (unsigned long long)__builtin_bit_cast(unsigned int, hn);
      // L2 copy first (latency-critical for same-XCD consumers), then IF$
      __hip_atomic_store(slotL2 + k0h + u, pk, __ATOMIC_RELAXED,
                         __HIP_MEMORY_SCOPE_WORKGROUP);
      __hip_atomic_store(slotIF + k0h + u, pk, __ATOMIC_RELAXED,
                         __HIP_MEMORY_SCOPE_AGENT);
      if (u == 0) {
        const size_t so = ((size_t)(t & 3) * B_ + b) * 16 + wg;
        const unsigned long long tagw = (unsigned long long)(unsigned int)t << 32;
        __hip_atomic_store(sentL2 + so, tagw, __ATOMIC_RELAXED,
                           __HIP_MEMORY_SCOPE_WORKGROUP);
        __hip_atomic_store(sentIF + so, tagw, __ATOMIC_RELAXED,
                           __HIP_MEMORY_SCOPE_AGENT);
      }
      r_out[((size_t)b * S_ + t) * H_ + k0h + u] = hn;
      if (t == S_ - 1) {
        hT[b * H_ + k0h + u] = hn;
        cT[b * H_ + k0h + u] = cn;
      }
    }

    if (t + 1 < S_) {
      // ---- detect: lanes 0..15, hybrid L2-RMW poll with IF$ fallback ----
      if (tid < 16) {
        const size_t so = ((size_t)(t & 3) * B_ + b) * 16 + tid;
        const unsigned int want = (unsigned int)t;
        for (int it = 0;; ++it) {
          unsigned long long w;
          if ((it & 3) != 3) {
            // atomic RMW executes at the L2 -> fresh, no L1, no fence
            w = __hip_atomic_fetch_add(sentL2 + so, 0ull, __ATOMIC_RELAXED,
                                       __HIP_MEMORY_SCOPE_WORKGROUP);
          } else {
            // authoritative IF$ copy (forward progress w/o XCD assumption)
            w = __hip_atomic_load(sentIF + so, __ATOMIC_RELAXED,
                                  __HIP_MEMORY_SCOPE_AGENT);
          }
          if ((unsigned int)(w >> 32) == want) break;
        }
      }
      __syncthreads();   // B: all 16 producers have published

      // ---- payload: L1-invalidate, then plain L2 loads, tag-verified ----
      __threadfence();   // acquire-ish: invalidates vector L1
      const unsigned int want = (unsigned int)t;
      unsigned long long v0 = __hip_atomic_load(slotL2 + tid, __ATOMIC_RELAXED,
                                                __HIP_MEMORY_SCOPE_WORKGROUP);
      unsigned long long v1 = __hip_atomic_load(slotL2 + tid + 256, __ATOMIC_RELAXED,
                                                __HIP_MEMORY_SCOPE_WORKGROUP);
      int it = 0;
      while ((((unsigned int)(v0 >> 32)) ^ want) |
             (((unsigned int)(v1 >> 32)) ^ want)) {
        ++it;
        if ((it & 3) == 3) {
          if ((unsigned int)(v0 >> 32) != want)
            v0 = __hip_atomic_load(slotIF + tid, __ATOMIC_RELAXED,
                                   __HIP_MEMORY_SCOPE_AGENT);
          if ((unsigned int)(v1 >> 32) != want)
            v1 = __hip_atomic_load(slotIF + tid + 256, __ATOMIC_RELAXED,
                                   __HIP_MEMORY_SCOPE_AGENT);
        } else {
          __threadfence();  // refresh L1 so the L2 re-read is fresh
          if ((unsigned int)(v0 >> 32) != want)
            v0 = __hip_atomic_load(slotL2 + tid, __ATOMIC_RELAXED,
                                   __HIP_MEMORY_SCOPE_WORKGROUP);
          if ((unsigned int)(v1 >> 32) != want)
            v1 = __hip_atomic_load(slotL2 + tid + 256, __ATOMIC_RELAXED,
                                   __HIP_MEMORY_SCOPE_WORKGROUP);
        }
      }
      h_lds[buf ^ 1][tid]       = lo32f(v0);
      h_lds[buf ^ 1][tid + 256] = lo32f(v1);

      // ---- G(t+1) prefetch: issued last, drains under barrier + next dot ----
      if (khalf == 0) gval = gbase[(size_t)(t + 1) * 2048 + gcol];
      __syncthreads();   // C: h(t) staged for next dot
      buf ^= 1;
    }
  }
}

// ---------------------------------------------------------------------------
// ws layout (bytes):
//   [0, 256MB)              : F [32768,1536] fp32 (a|v|l), reused as G [32768,2048]
//   [256MB, 320MB)          : CTX [32768,512]
//   [320MB, 384MB)          : FU  [32768,512]
//   [384MB, +256KB)         : ringL2 [4][16][512] u64 (workgroup-scope stores)
//   [+256KB, +512KB)        : ringIF [4][16][512] u64 (agent-scope stores)
//   [+512KB, +520KB)        : sentL2 [4][16][16] u64
//   [+520KB, +528KB)        : sentIF [4][16][16] u64
// Total < 385 MB.
// ---------------------------------------------------------------------------
extern "C" void kernel_launch(void* const* d_in, const int* in_sizes, int n_in,
                              void* d_out, int out_size, void* d_ws, size_t ws_size,
                              hipStream_t stream)
{
  const float* a_in = (const float*)d_in[0];
  const float* v_in = (const float*)d_in[1];
  const float* l_in = (const float*)d_in[2];
  const float* h0   = (const float*)d_in[3];
  const float* c0   = (const float*)d_in[4];
  const float* Wa = (const float*)d_in[5];   const float* ba = (const float*)d_in[6];
  const float* Wv = (const float*)d_in[7];   const float* bv = (const float*)d_in[8];
  const float* Wl = (const float*)d_in[9];   const float* bl = (const float*)d_in[10];
  const float* Wc = (const float*)d_in[11];  const float* bc = (const float*)d_in[12];
  const float* Wih = (const float*)d_in[13]; const float* Whh = (const float*)d_in[14];
  const float* bih = (const float*)d_in[15]; const float* bhh = (const float*)d_in[16];

  char* ws = (char*)d_ws;
  float* Fbuf = (float*)ws;                       // also Gbuf after fusion
  float* Gbuf = (float*)ws;
  float* CTX  = (float*)(ws + 268435456ull);
  float* FU   = (float*)(ws + 335544320ull);
  unsigned long long* ringL2 = (unsigned long long*)(ws + 402653184ull);
  unsigned long long* ringIF = (unsigned long long*)(ws + 402653184ull + 262144ull);
  unsigned long long* sentL2 = (unsigned long long*)(ws + 402653184ull + 524288ull);
  unsigned long long* sentIF = (unsigned long long*)(ws + 402653184ull + 532480ull);

  dim3 blk(256);
  // projections into F (ld 1536): a|v|l
  gemm_xwt<0><<<dim3(256, 4), blk, 0, stream>>>(a_in, Wa, ba, nullptr, Fbuf + 0,    512,  1536);
  gemm_xwt<0><<<dim3(256, 4), blk, 0, stream>>>(v_in, Wv, bv, nullptr, Fbuf + 512,  768,  1536);
  gemm_xwt<0><<<dim3(256, 4), blk, 0, stream>>>(l_in, Wl, bl, nullptr, Fbuf + 1024, 1024, 1536);
  // context = tanh(F @ Wc^T + bc)
  gemm_xwt<1><<<dim3(256, 4), blk, 0, stream>>>(Fbuf, Wc, bc, nullptr, CTX, 1536, 512);
  // softmax-weighted fusion
  fusion_kernel<<<dim3(8192), blk, 0, stream>>>(Fbuf, CTX, FU);
  // G = FU @ Wih^T + bih + bhh   (overwrites F region — F is dead)
  gemm_xwt<0><<<dim3(256, 16), blk, 0, stream>>>(FU, Wih, bih, bhh, Gbuf, 512, 2048);
  // persistent sequential LSTM (dual-path L2/IF$ tag sync)
  float* out = (float*)d_out;
  lstm_kernel<<<dim3(256), blk, 0, stream>>>(Gbuf, Whh, h0, c0,
                                             ringL2, ringIF, sentL2, sentIF,
                                             out, out + 16777216ull,
                                             out + 16777216ull + 8192ull);
}

// Round 4
// 8997.365 us; speedup vs baseline: 4.4957x; 4.4957x over previous
//
#include <hip/hip_runtime.h>
#include <stdint.h>

#define B_ 16
#define S_ 2048
#define H_ 512
#define M_ (B_ * S_)  // 32768 rows in all big GEMMs

// ---------------------------------------------------------------------------
// GEMM: Y[M,N] = X[M,K] @ W[N,K]^T + b1[N] (+ b2[N]), optional tanh epilogue.
// 128x128 tile, BK=16, 256 threads, 8x8 micro-tile per thread. fp32 VALU.
// (unchanged)
// ---------------------------------------------------------------------------
template <int ACT>
__global__ __launch_bounds__(256) void gemm_xwt(
    const float* __restrict__ X, const float* __restrict__ W,
    const float* __restrict__ b1, const float* __restrict__ b2,
    float* __restrict__ Y, int K, int ldy)
{
  __shared__ float As[16][132];
  __shared__ float Bs[16][132];
  const int tid = threadIdx.x;
  const int bm = blockIdx.x, bn = blockIdx.y;
  const int ty = tid >> 4, tx = tid & 15;      // 16x16 thread grid
  const int lr = tid >> 2, lk = (tid & 3) << 2; // staging: 64 rows x 4 k-quads
  const float* Xb = X + (size_t)(bm * 128) * K;
  const float* Wb = W + (size_t)(bn * 128) * K;

  float acc[8][8] = {};

  for (int k0 = 0; k0 < K; k0 += 16) {
    float4 xa0 = *(const float4*)(Xb + (size_t)lr * K + k0 + lk);
    float4 xa1 = *(const float4*)(Xb + (size_t)(lr + 64) * K + k0 + lk);
    float4 wa0 = *(const float4*)(Wb + (size_t)lr * K + k0 + lk);
    float4 wa1 = *(const float4*)(Wb + (size_t)(lr + 64) * K + k0 + lk);
    __syncthreads();
    As[lk + 0][lr] = xa0.x; As[lk + 1][lr] = xa0.y; As[lk + 2][lr] = xa0.z; As[lk + 3][lr] = xa0.w;
    As[lk + 0][lr + 64] = xa1.x; As[lk + 1][lr + 64] = xa1.y; As[lk + 2][lr + 64] = xa1.z; As[lk + 3][lr + 64] = xa1.w;
    Bs[lk + 0][lr] = wa0.x; Bs[lk + 1][lr] = wa0.y; Bs[lk + 2][lr] = wa0.z; Bs[lk + 3][lr] = wa0.w;
    Bs[lk + 0][lr + 64] = wa1.x; Bs[lk + 1][lr + 64] = wa1.y; Bs[lk + 2][lr + 64] = wa1.z; Bs[lk + 3][lr + 64] = wa1.w;
    __syncthreads();
#pragma unroll
    for (int kk = 0; kk < 16; ++kk) {
      float4 a0 = *(const float4*)&As[kk][ty * 8];
      float4 a1 = *(const float4*)&As[kk][ty * 8 + 4];
      float4 b0 = *(const float4*)&Bs[kk][tx * 8];
      float4 b1v = *(const float4*)&Bs[kk][tx * 8 + 4];
      float av[8] = {a0.x, a0.y, a0.z, a0.w, a1.x, a1.y, a1.z, a1.w};
      float bv[8] = {b0.x, b0.y, b0.z, b0.w, b1v.x, b1v.y, b1v.z, b1v.w};
#pragma unroll
      for (int i = 0; i < 8; ++i)
#pragma unroll
        for (int j = 0; j < 8; ++j) acc[i][j] += av[i] * bv[j];
    }
  }

  const int ncol0 = bn * 128 + tx * 8;
  float bias[8];
#pragma unroll
  for (int j = 0; j < 8; ++j) {
    float bb = b1[ncol0 + j];
    if (b2) bb += b2[ncol0 + j];
    bias[j] = bb;
  }
#pragma unroll
  for (int i = 0; i < 8; ++i) {
    size_t row = (size_t)bm * 128 + ty * 8 + i;
    float* yp = Y + row * (size_t)ldy + ncol0;
    float out[8];
#pragma unroll
    for (int j = 0; j < 8; ++j) {
      float v = acc[i][j] + bias[j];
      if (ACT) v = tanhf(v);
      out[j] = v;
    }
    *(float4*)(yp)     = make_float4(out[0], out[1], out[2], out[3]);
    *(float4*)(yp + 4) = make_float4(out[4], out[5], out[6], out[7]);
  }
}

// ---------------------------------------------------------------------------
// Attention fusion (unchanged).
// ---------------------------------------------------------------------------
__global__ __launch_bounds__(256) void fusion_kernel(
    const float* __restrict__ F,    // [M, 1536] = a|v|l
    const float* __restrict__ CTX,  // [M, 512]
    float* __restrict__ FU)         // [M, 512]
{
  const int row = blockIdx.x * 4 + (threadIdx.x >> 6);
  const int lane = threadIdx.x & 63;
  const float* a = F + (size_t)row * 1536;
  const float* v = a + 512;
  const float* l = a + 1024;
  const float* c = CTX + (size_t)row * 512;
  float sa = 0.f, sv = 0.f, sl = 0.f;
  for (int k = lane; k < 512; k += 64) {
    float cv = c[k];
    sa += a[k] * cv; sv += v[k] * cv; sl += l[k] * cv;
  }
#pragma unroll
  for (int off = 1; off < 64; off <<= 1) {
    sa += __shfl_xor(sa, off);
    sv += __shfl_xor(sv, off);
    sl += __shfl_xor(sl, off);
  }
  float m = fmaxf(sa, fmaxf(sv, sl));
  float ea = expf(sa - m), ev = expf(sv - m), el = expf(sl - m);
  float inv = 1.0f / (ea + ev + el);
  float wa = ea * inv, wv = ev * inv, wl = el * inv;
  float* fu = FU + (size_t)row * 512;
  for (int k = lane; k < 512; k += 64)
    fu[k] = wa * a[k] + wv * v[k] + wl * l[k];
}

// ---------------------------------------------------------------------------
// Persistent LSTM v5: v3 protocol, LDS-efficient dot + direct payload spin.
//
// v4 post-mortem: workgroup-scope stores linger in producer L1 -> consumers
// stall until eviction. No fast cross-WG path below agent scope. Reverted.
//
// v5 changes vs v3 (protocol & math semantics preserved):
//  DOT RESTRUCTURE (the 2^29 bank-conflict counter = 1024 cy/WG/step, all
//  from the old dot; plus 256 b128-instrs/WG with zero h-reuse):
//   - thread (grp=tid>>3, j=tid&7) owns 4 gate rows (4*grp..4*grp+3) over
//     k in [64j, 64j+64): each h float4 feeds 4 FMAs -> 16 ds_read_b128
//     per thread (was 64), 64 per WG (was 256).
//   - rotation m=(i+j)&15 on the h-chunk order; Whh registers loaded
//     pre-rotated at setup so all register indices stay compile-time.
//     For fixed i the 8 j-lanes hit 8 distinct 4-bank groups -> conflict-
//     free, full 1024B useful data per instruction.
//   - 8-lane __shfl_xor reduce (masks 1,2,4) completes each row's dot.
//  SYNC: drop the sentinel stage (v3 proved spin traffic irrelevant);
//   all 256 threads spin directly on their own 2 tagged payload words,
//   both loads issued per iteration -> ONE round trip per poll.
//   Two barriers/step (was 3). Ring depth 4, tag-in-word, no fences.
//   Lap-safety: publish(t) precedes poll(t) -> max published tag anywhere
//   is t+1 while any WG still polls t; slot (t&3) can't be overwritten
//   before everyone consumed t. Poison/stale tags never match.
// ---------------------------------------------------------------------------
__device__ __forceinline__ float sigf(float x) { return 1.f / (1.f + expf(-x)); }
__device__ __forceinline__ float lo32f(unsigned long long w) {
  return __builtin_bit_cast(float, (unsigned int)w);
}

__global__ __launch_bounds__(256, 1) void lstm_kernel(
    const float* __restrict__ G,    // [B*S, 2048] precomputed x@Wih.T + biases
    const float* __restrict__ Whh,  // [2048, 512]
    const float* __restrict__ h0,   // [B, 512]
    const float* __restrict__ c0,   // [B, 512]
    unsigned long long* __restrict__ ring,  // [4][B][512] tagged h words
    float* __restrict__ r_out,      // [B, S, 512]
    float* __restrict__ hT,         // [B, 512]
    float* __restrict__ cT)         // [B, 512]
{
  const int bi = blockIdx.x;
  const int b  = ((bi & 7) << 1) | ((bi >> 3) & 1);  // 16 WGs/batch -> 1 XCD
  const int wg = bi >> 4;
  const int k0h = wg << 5;  // hidden-slice base (32 units)
  const int tid = threadIdx.x;

  __shared__ float h_lds[2][512];   // double-buffered h
  __shared__ float gates_lds[128];
  __shared__ float c_lds[32];

  // ---- dot mapping: 4 rows/thread, 8-lane K-split, rotated chunks ----
  const int grp = tid >> 3;        // 0..31 -> rows 4*grp..4*grp+3
  const int j   = tid & 7;         // k-segment [64j, 64j+64)
  const int lr0 = grp << 2;        // local row base (multiple of 4, same gate block)
  const int grow0 = ((lr0 >> 5) << 9) + k0h + (lr0 & 31);  // global gate row

  // Whh slice into registers, PRE-ROTATED: wq[r][i] covers k-chunk m=(i+j)&15
  float4 wq[4][16];
#pragma unroll
  for (int i = 0; i < 16; ++i) {
    const int m = (i + j) & 15;
#pragma unroll
    for (int r = 0; r < 4; ++r)
      wq[r][i] = *(const float4*)(Whh + (size_t)(grow0 + r) * 512 + j * 64 + m * 4);
  }

  const float* gbase = G + (size_t)b * S_ * 2048;

  if (tid < 32) c_lds[tid] = c0[b * H_ + k0h + tid];
  h_lds[0][tid]       = h0[b * H_ + tid];
  h_lds[0][tid + 256] = h0[b * H_ + tid + 256];
  // G(0) prefetch: lanes j<4 hold G for row grow0+j
  float gval = (j < 4) ? gbase[grow0 + j] : 0.f;
  __syncthreads();

  int buf = 0;
  for (int t = 0; t < S_; ++t) {
    // ---- dot over h(t-1): 16 conflict-free b128 reads, 4x reuse ----
    const float* hb = &h_lds[buf][j << 6];
    float4 a0 = make_float4(0.f, 0.f, 0.f, 0.f);
    float4 a1 = a0, a2 = a0, a3 = a0;
#pragma unroll
    for (int i = 0; i < 16; ++i) {
      const int m = (i + j) & 15;
      float4 hv = *(const float4*)(hb + (m << 2));
      a0.x += wq[0][i].x * hv.x; a0.y += wq[0][i].y * hv.y;
      a0.z += wq[0][i].z * hv.z; a0.w += wq[0][i].w * hv.w;
      a1.x += wq[1][i].x * hv.x; a1.y += wq[1][i].y * hv.y;
      a1.z += wq[1][i].z * hv.z; a1.w += wq[1][i].w * hv.w;
      a2.x += wq[2][i].x * hv.x; a2.y += wq[2][i].y * hv.y;
      a2.z += wq[2][i].z * hv.z; a2.w += wq[2][i].w * hv.w;
      a3.x += wq[3][i].x * hv.x; a3.y += wq[3][i].y * hv.y;
      a3.z += wq[3][i].z * hv.z; a3.w += wq[3][i].w * hv.w;
    }
    float s0 = (a0.x + a0.y) + (a0.z + a0.w);
    float s1 = (a1.x + a1.y) + (a1.z + a1.w);
    float s2 = (a2.x + a2.y) + (a2.z + a2.w);
    float s3 = (a3.x + a3.y) + (a3.z + a3.w);
#pragma unroll
    for (int off = 1; off < 8; off <<= 1) {
      s0 += __shfl_xor(s0, off);
      s1 += __shfl_xor(s1, off);
      s2 += __shfl_xor(s2, off);
      s3 += __shfl_xor(s3, off);
    }
    if (j < 4) {
      float sv = (j == 0) ? s0 : (j == 1) ? s1 : (j == 2) ? s2 : s3;
      gates_lds[lr0 + j] = sv + gval;
    }
    __syncthreads();   // A: gates ready

    unsigned long long* slot = ring + ((size_t)(t & 3) * B_ + b) * H_;

    // ---- producer tail: 32 lanes, nonlinearity + tagged publish ----
    if (tid < 32) {
      const int u = tid;
      float ip = gates_lds[u], fp = gates_lds[32 + u];
      float gp = gates_lds[64 + u], op = gates_lds[96 + u];
      float ig = sigf(ip), fg = sigf(fp);
      float gg = tanhf(gp), og = sigf(op);
      float cn = fg * c_lds[u] + ig * gg;
      c_lds[u] = cn;
      float hn = og * tanhf(cn);
      unsigned long long pk =
          ((unsigned long long)(unsigned int)t << 32) |
          (unsigned long long)__builtin_bit_cast(unsigned int, hn);
      __hip_atomic_store(slot + k0h + u, pk, __ATOMIC_RELAXED,
                         __HIP_MEMORY_SCOPE_AGENT);
      r_out[((size_t)b * S_ + t) * H_ + k0h + u] = hn;
      if (t == S_ - 1) {
        hT[b * H_ + k0h + u] = hn;
        cT[b * H_ + k0h + u] = cn;
      }
    }

    if (t + 1 < S_) {
      // ---- direct payload spin: both loads in flight, one RT/iteration ----
      const unsigned int want = (unsigned int)t;
      unsigned long long v0, v1;
      for (;;) {
        v0 = __hip_atomic_load(slot + tid, __ATOMIC_RELAXED,
                               __HIP_MEMORY_SCOPE_AGENT);
        v1 = __hip_atomic_load(slot + tid + 256, __ATOMIC_RELAXED,
                               __HIP_MEMORY_SCOPE_AGENT);
        if (!(((unsigned int)(v0 >> 32) ^ want) |
              ((unsigned int)(v1 >> 32) ^ want))) break;
      }
      h_lds[buf ^ 1][tid]       = lo32f(v0);
      h_lds[buf ^ 1][tid + 256] = lo32f(v1);

      // ---- G(t+1) prefetch: issued last, drains under barrier + next dot ----
      if (j < 4) gval = gbase[(size_t)(t + 1) * 2048 + grow0 + j];
      __syncthreads();   // C: h(t) staged for next dot
      buf ^= 1;
    }
  }
}

// ---------------------------------------------------------------------------
// ws layout (bytes):
//   [0, 256MB)            : F [32768,1536] fp32 (a|v|l), reused as G [32768,2048]
//   [256MB, 320MB)        : CTX [32768,512]
//   [320MB, 384MB)        : FU  [32768,512]
//   [384MB, +256KB)       : tagged h ring [4][16][512] x u64
// Total < 385 MB.
// ---------------------------------------------------------------------------
extern "C" void kernel_launch(void* const* d_in, const int* in_sizes, int n_in,
                              void* d_out, int out_size, void* d_ws, size_t ws_size,
                              hipStream_t stream)
{
  const float* a_in = (const float*)d_in[0];
  const float* v_in = (const float*)d_in[1];
  const float* l_in = (const float*)d_in[2];
  const float* h0   = (const float*)d_in[3];
  const float* c0   = (const float*)d_in[4];
  const float* Wa = (const float*)d_in[5];   const float* ba = (const float*)d_in[6];
  const float* Wv = (const float*)d_in[7];   const float* bv = (const float*)d_in[8];
  const float* Wl = (const float*)d_in[9];   const float* bl = (const float*)d_in[10];
  const float* Wc = (const float*)d_in[11];  const float* bc = (const float*)d_in[12];
  const float* Wih = (const float*)d_in[13]; const float* Whh = (const float*)d_in[14];
  const float* bih = (const float*)d_in[15]; const float* bhh = (const float*)d_in[16];

  char* ws = (char*)d_ws;
  float* Fbuf = (float*)ws;                       // also Gbuf after fusion
  float* Gbuf = (float*)ws;
  float* CTX  = (float*)(ws + 268435456ull);
  float* FU   = (float*)(ws + 335544320ull);
  unsigned long long* ringp = (unsigned long long*)(ws + 402653184ull);

  dim3 blk(256);
  // projections into F (ld 1536): a|v|l
  gemm_xwt<0><<<dim3(256, 4), blk, 0, stream>>>(a_in, Wa, ba, nullptr, Fbuf + 0,    512,  1536);
  gemm_xwt<0><<<dim3(256, 4), blk, 0, stream>>>(v_in, Wv, bv, nullptr, Fbuf + 512,  768,  1536);
  gemm_xwt<0><<<dim3(256, 4), blk, 0, stream>>>(l_in, Wl, bl, nullptr, Fbuf + 1024, 1024, 1536);
  // context = tanh(F @ Wc^T + bc)
  gemm_xwt<1><<<dim3(256, 4), blk, 0, stream>>>(Fbuf, Wc, bc, nullptr, CTX, 1536, 512);
  // softmax-weighted fusion
  fusion_kernel<<<dim3(8192), blk, 0, stream>>>(Fbuf, CTX, FU);
  // G = FU @ Wih^T + bih + bhh   (overwrites F region — F is dead)
  gemm_xwt<0><<<dim3(256, 16), blk, 0, stream>>>(FU, Wih, bih, bhh, Gbuf, 512, 2048);
  // persistent sequential LSTM (direct payload tag spin)
  float* out = (float*)d_out;
  lstm_kernel<<<dim3(256), blk, 0, stream>>>(Gbuf, Whh, h0, c0, ringp,
                                             out, out + 16777216ull,
                                             out + 16777216ull + 8192ull);
}